// Round 4
// baseline (885.468 us; speedup 1.0000x reference)
//
#include <hip/hip_runtime.h>
#include <hip/hip_bf16.h>

#define NEG_SLOPE 0.2f

using bf16 = __hip_bfloat16;

__device__ __forceinline__ float tof(bf16 v) { return __bfloat162float(v); }
__device__ __forceinline__ float tof(float v) { return v; }
__device__ __forceinline__ void store_val(bf16* p, float v) { *p = __float2bfloat16(v); }
__device__ __forceinline__ void store_val(float* p, float v) { *p = v; }

// load two consecutive elements as floats
__device__ __forceinline__ float2 load2(const bf16* p) {
    unsigned int u = *(const unsigned int*)p;
    float2 r;
    r.x = __uint_as_float((u & 0xffffu) << 16);
    r.y = __uint_as_float(u & 0xffff0000u);
    return r;
}
__device__ __forceinline__ float2 load2(const float* p) { return *(const float2*)p; }

// true if first 128 half-words of p look like fp32 bit patterns (not bf16 N(0,1))
__device__ __forceinline__ int detect_fp32(const void* p_) {
    const unsigned short* p = (const unsigned short*)p_;
    int f32 = 0;
    for (int i = 0; i < 128; ++i) {
        float v = __uint_as_float(((unsigned int)p[i]) << 16);
        if (!(fabsf(v) < 100.f)) f32 = 1;  // catches NaN too
    }
    return f32;
}

// Stage NS rows of F elems into LDS (row stride FP, fp32) from self(1)+neigh(NS-1).
template <typename T, int F, int NS, int FP>
__device__ __forceinline__ void stage(float* xs, const T* self, const T* neigh, int tid) {
    constexpr int V = 16 / sizeof(T);
    constexpr int TOT = NS * F / V;
    for (int i = tid; i < TOT; i += 256) {
        int e = i * V;
        int s = e / F, f = e % F;
        const T* src = (s == 0) ? (self + f) : (neigh + (size_t)(s - 1) * F + f);
        uint4 raw = *(const uint4*)src;
        const T* hv = (const T*)&raw;
        float* dst = &xs[s * FP + f];
#pragma unroll
        for (int k = 0; k < V; ++k) dst[k] = tof(hv[k]);
    }
}

// logits (2 threads per (sample,head) unit) + leaky_relu + softmax. Caller syncs before.
template <typename T, int F, int NS, int FP>
__device__ __forceinline__ void attention(const float* xs, const T* a_self,
                                          const T* a_neigh, float (*attn)[26],
                                          float* lsf, int tid) {
    constexpr int NU = (NS + 1) * 4;  // units: NS neighbor-logits + self-logit, x4 heads
    constexpr int HL = F / 2;         // half dot length
    int u = tid >> 1;
    float acc = 0.f;
    if (u < NU) {
        int s = u >> 2, h = u & 3;
        const T* a = (s < NS) ? (a_neigh + (size_t)h * F) : (a_self + (size_t)h * F);
        const float* xrow = xs + (size_t)(s < NS ? s : 0) * FP;
        int f0 = (tid & 1) * HL;
        float a0 = 0.f, a1 = 0.f, a2 = 0.f, a3 = 0.f;
        for (int f = f0; f < f0 + HL; f += 4) {
            a0 += xrow[f + 0] * tof(a[f + 0]);
            a1 += xrow[f + 1] * tof(a[f + 1]);
            a2 += xrow[f + 2] * tof(a[f + 2]);
            a3 += xrow[f + 3] * tof(a[f + 3]);
        }
        acc = (a0 + a1) + (a2 + a3);
    }
    float other = __shfl_xor(acc, 1);
    if (u < NU && (tid & 1) == 0) {
        float tot = acc + other;
        int s = u >> 2, h = u & 3;
        if (s < NS) attn[h][s] = tot;
        else        lsf[h] = tot;
    }
    __syncthreads();
    if (tid < 4) {
        int h = tid;
        float ls = lsf[h];
        float v[NS];
        float m = -1e30f;
#pragma unroll
        for (int s = 0; s < NS; ++s) {
            float x = ls + attn[h][s];
            x = (x > 0.f) ? x : NEG_SLOPE * x;
            v[s] = x;
            m = fmaxf(m, x);
        }
        float sum = 0.f;
#pragma unroll
        for (int s = 0; s < NS; ++s) { float e = __expf(v[s] - m); v[s] = e; sum += e; }
        float inv = 1.f / sum;
#pragma unroll
        for (int s = 0; s < NS; ++s) attn[h][s] = v[s] * inv;
    }
    __syncthreads();
}

// xbar[h][f] = sum_s attn[h][s] * xs[s][f]
template <int F, int NS, int FP>
__device__ __forceinline__ void aggregate(const float* xs, const float (*attn)[26],
                                          float* xbar, int tid) {
    constexpr int FCH = F / 256;
    float acc[4][FCH];
#pragma unroll
    for (int h = 0; h < 4; ++h)
#pragma unroll
        for (int c = 0; c < FCH; ++c) acc[h][c] = 0.f;
    for (int s = 0; s < NS; ++s) {
        float w0 = attn[0][s], w1 = attn[1][s], w2 = attn[2][s], w3 = attn[3][s];
#pragma unroll
        for (int c = 0; c < FCH; ++c) {
            float xv = xs[(size_t)s * FP + tid + c * 256];
            acc[0][c] += w0 * xv;
            acc[1][c] += w1 * xv;
            acc[2][c] += w2 * xv;
            acc[3][c] += w3 * xv;
        }
    }
#pragma unroll
    for (int c = 0; c < FCH; ++c)
#pragma unroll
        for (int h = 0; h < 4; ++h)
            xbar[h * F + tid + c * 256] = acc[h][c];
}

// thread tid -> head h = tid>>6, d-pair d0 = 2*(tid&63); returns {out[h*128+d0], +1}
template <typename T, int F>
__device__ __forceinline__ float2 transform_pair(const float* xbar, const T* w, int tid) {
    int h = tid >> 6;
    int d0 = (tid & 63) * 2;
    const T* wp = w + ((size_t)h * F) * 128 + d0;
    const float* xb = xbar + (size_t)h * F;
    float r0 = 0.f, r1 = 0.f;
    for (int f = 0; f < F; ++f) {
        float xv = xb[f];
        float2 wv = load2(wp + (size_t)f * 128);
        r0 += xv * wv.x;
        r1 += xv * wv.y;
    }
    return make_float2(r0, r1);
}

// ---------------- Kernel 1: layer-0 GAT, one block per node ----------------
template <typename T, int NS>
__device__ __forceinline__ void layer0_node(
    const T* self, const T* neigh, const T* w0, const T* a0s, const T* a0n,
    float* h_ws, float* xs, float* xbar, float (*attn)[26], float* lsf, int tid)
{
    stage<T, 256, NS, 260>(xs, self, neigh, tid);
    __syncthreads();
    attention<T, 256, NS, 260>(xs, a0s, a0n, attn, lsf, tid);
    aggregate<256, NS, 260>(xs, attn, xbar, tid);
    __syncthreads();
    float2 r = transform_pair<T, 256>(xbar, w0, tid);
    int h = tid >> 6, d0 = (tid & 63) * 2;
    *(float2*)&h_ws[h * 128 + d0] = r;
}

__global__ __launch_bounds__(256) void gat_layer0(
    const void* x0, const void* x1, const void* x2, const void* w0,
    const void* a0s, const void* a0n, float* h0_ws, float* h1_ws, int B)
{
    const int n = blockIdx.x;
    const int tid = threadIdx.x;

    __shared__ float xs[26 * 260];
    __shared__ float xbar[4 * 256];
    __shared__ float attn[4][26];
    __shared__ float lsf[4];
    __shared__ int is_fp32;

    if (tid == 0) is_fp32 = detect_fp32(x0);
    __syncthreads();

    if (!is_fp32) {
        const bf16* X0 = (const bf16*)x0; const bf16* X1 = (const bf16*)x1;
        const bf16* X2 = (const bf16*)x2; const bf16* W0 = (const bf16*)w0;
        const bf16* AS = (const bf16*)a0s; const bf16* AN = (const bf16*)a0n;
        if (n < B) {
            layer0_node<bf16, 11>(X0 + (size_t)n * 256, X1 + (size_t)n * 2560,
                                  W0, AS, AN, h0_ws + (size_t)n * 512,
                                  xs, xbar, attn, lsf, tid);
        } else {
            int m = n - B, b = m / 10, p = m % 10;
            layer0_node<bf16, 26>(X1 + ((size_t)b * 10 + p) * 256,
                                  X2 + ((size_t)b * 250 + (size_t)p * 25) * 256,
                                  W0, AS, AN, h1_ws + (size_t)m * 512,
                                  xs, xbar, attn, lsf, tid);
        }
    } else {
        const float* X0 = (const float*)x0; const float* X1 = (const float*)x1;
        const float* X2 = (const float*)x2; const float* W0 = (const float*)w0;
        const float* AS = (const float*)a0s; const float* AN = (const float*)a0n;
        if (n < B) {
            layer0_node<float, 11>(X0 + (size_t)n * 256, X1 + (size_t)n * 2560,
                                   W0, AS, AN, h0_ws + (size_t)n * 512,
                                   xs, xbar, attn, lsf, tid);
        } else {
            int m = n - B, b = m / 10, p = m % 10;
            layer0_node<float, 26>(X1 + ((size_t)b * 10 + p) * 256,
                                   X2 + ((size_t)b * 250 + (size_t)p * 25) * 256,
                                   W0, AS, AN, h1_ws + (size_t)m * 512,
                                   xs, xbar, attn, lsf, tid);
        }
    }
}

// ------------- Kernel 2: layer-1 GAT + projection, one block per root -------------
template <typename T>
__device__ __forceinline__ void layer1_body(
    const float* h0row, const float* h1rows, const T* w1, const T* a1s,
    const T* a1n, const T* fcw, T* outp, float* hs, float* xbar,
    float (*attn)[26], float* lsf, float* hroot, int tid)
{
    // stage 11 rows of 512 fp32 (row stride 516)
    for (int i = tid; i < 11 * 512 / 4; i += 256) {
        int e = i * 4;
        int s = e / 512, f = e % 512;
        const float* src = (s == 0) ? (h0row + f) : (h1rows + (size_t)(s - 1) * 512 + f);
        float4 v = *(const float4*)src;
        float* dst = &hs[s * 516 + f];
        dst[0] = v.x; dst[1] = v.y; dst[2] = v.z; dst[3] = v.w;
    }
    __syncthreads();
    attention<T, 512, 11, 516>(hs, a1s, a1n, attn, lsf, tid);
    aggregate<512, 11, 516>(hs, attn, xbar, tid);
    __syncthreads();
    float2 r = transform_pair<T, 512>(xbar, w1, tid);
    int h = tid >> 6, d0 = (tid & 63) * 2;
    hroot[h * 128 + d0] = r.x;
    hroot[h * 128 + d0 + 1] = r.y;
    __syncthreads();
    // projection: out[j] = <hroot, fcw[:, j]>
    const T* fp = fcw + tid;
    float a0 = 0.f, a1 = 0.f, a2 = 0.f, a3 = 0.f;
    for (int f = 0; f < 512; f += 4) {
        a0 += hroot[f + 0] * tof(fp[(size_t)(f + 0) * 256]);
        a1 += hroot[f + 1] * tof(fp[(size_t)(f + 1) * 256]);
        a2 += hroot[f + 2] * tof(fp[(size_t)(f + 2) * 256]);
        a3 += hroot[f + 3] * tof(fp[(size_t)(f + 3) * 256]);
    }
    store_val(outp + tid, (a0 + a1) + (a2 + a3));
}

__global__ __launch_bounds__(256) void gat_layer1(
    const float* h0_ws, const float* h1_ws, const void* w1, const void* a1s,
    const void* a1n, const void* fcw, void* out)
{
    const int b = blockIdx.x;
    const int tid = threadIdx.x;

    __shared__ float hs[11 * 516];
    __shared__ float xbar[4 * 512];
    __shared__ float attn[4][26];
    __shared__ float lsf[4];
    __shared__ float hroot[512];
    __shared__ int is_fp32;

    if (tid == 0) is_fp32 = detect_fp32(w1);
    __syncthreads();

    const float* h0row = h0_ws + (size_t)b * 512;
    const float* h1rows = h1_ws + (size_t)b * 10 * 512;
    if (!is_fp32)
        layer1_body<bf16>(h0row, h1rows, (const bf16*)w1, (const bf16*)a1s,
                          (const bf16*)a1n, (const bf16*)fcw,
                          (bf16*)out + (size_t)b * 256,
                          hs, xbar, attn, lsf, hroot, tid);
    else
        layer1_body<float>(h0row, h1rows, (const float*)w1, (const float*)a1s,
                           (const float*)a1n, (const float*)fcw,
                           (float*)out + (size_t)b * 256,
                           hs, xbar, attn, lsf, hroot, tid);
}

// ---------------- Fallback: proven round-3 fused kernel (no workspace) ----------------
template <typename T>
__device__ __forceinline__ void gat_body(
    const T* x0, const T* x1, const T* x2, const T* w0, const T* a0s,
    const T* a0n, const T* w1, const T* a1s, const T* a1n, const T* fcw,
    T* out, float* xs, float* hs, float* xbar, float (*attn)[26],
    float* lsf, float* hroot, int b, int tid)
{
    for (int p = 0; p < 10; ++p) {
        const T* self  = x1 + ((size_t)b * 10 + p) * 256;
        const T* neigh = x2 + ((size_t)b * 250 + (size_t)p * 25) * 256;
        stage<T, 256, 26, 260>(xs, self, neigh, tid);
        __syncthreads();
        attention<T, 256, 26, 260>(xs, a0s, a0n, attn, lsf, tid);
        aggregate<256, 26, 260>(xs, attn, xbar, tid);
        __syncthreads();
        float2 r = transform_pair<T, 256>(xbar, w0, tid);
        int h = tid >> 6, d0 = (tid & 63) * 2;
        hs[(p + 1) * 516 + h * 128 + d0] = r.x;
        hs[(p + 1) * 516 + h * 128 + d0 + 1] = r.y;
        __syncthreads();
    }
    stage<T, 256, 11, 260>(xs, x0 + (size_t)b * 256, x1 + (size_t)b * 2560, tid);
    __syncthreads();
    attention<T, 256, 11, 260>(xs, a0s, a0n, attn, lsf, tid);
    aggregate<256, 11, 260>(xs, attn, xbar, tid);
    __syncthreads();
    {
        float2 r = transform_pair<T, 256>(xbar, w0, tid);
        int h = tid >> 6, d0 = (tid & 63) * 2;
        hs[h * 128 + d0] = r.x;
        hs[h * 128 + d0 + 1] = r.y;
    }
    __syncthreads();
    attention<T, 512, 11, 516>(hs, a1s, a1n, attn, lsf, tid);
    aggregate<512, 11, 516>(hs, attn, xbar, tid);
    __syncthreads();
    {
        float2 r = transform_pair<T, 512>(xbar, w1, tid);
        int h = tid >> 6, d0 = (tid & 63) * 2;
        hroot[h * 128 + d0] = r.x;
        hroot[h * 128 + d0 + 1] = r.y;
    }
    __syncthreads();
    const T* fp = fcw + tid;
    float a0 = 0.f, a1 = 0.f, a2 = 0.f, a3 = 0.f;
    for (int f = 0; f < 512; f += 4) {
        a0 += hroot[f + 0] * tof(fp[(size_t)(f + 0) * 256]);
        a1 += hroot[f + 1] * tof(fp[(size_t)(f + 1) * 256]);
        a2 += hroot[f + 2] * tof(fp[(size_t)(f + 2) * 256]);
        a3 += hroot[f + 3] * tof(fp[(size_t)(f + 3) * 256]);
    }
    store_val(&out[(size_t)b * 256 + tid], (a0 + a1) + (a2 + a3));
}

__global__ __launch_bounds__(256) void gat_fused(
    const void* x0, const void* x1, const void* x2, const void* w0,
    const void* a0s, const void* a0n, const void* w1, const void* a1s,
    const void* a1n, const void* fcw, void* out)
{
    const int b = blockIdx.x;
    const int tid = threadIdx.x;

    __shared__ float xs[26 * 260];
    __shared__ float hs[11 * 516];
    __shared__ float xbar[4 * 512];
    __shared__ float attn[4][26];
    __shared__ float lsf[4];
    __shared__ float hroot[512];
    __shared__ int is_fp32;

    if (tid == 0) is_fp32 = detect_fp32(x0);
    __syncthreads();

    if (is_fp32)
        gat_body<float>((const float*)x0, (const float*)x1, (const float*)x2,
                        (const float*)w0, (const float*)a0s, (const float*)a0n,
                        (const float*)w1, (const float*)a1s, (const float*)a1n,
                        (const float*)fcw, (float*)out,
                        xs, hs, xbar, attn, lsf, hroot, b, tid);
    else
        gat_body<bf16>((const bf16*)x0, (const bf16*)x1, (const bf16*)x2,
                       (const bf16*)w0, (const bf16*)a0s, (const bf16*)a0n,
                       (const bf16*)w1, (const bf16*)a1s, (const bf16*)a1n,
                       (const bf16*)fcw, (bf16*)out,
                       xs, hs, xbar, attn, lsf, hroot, b, tid);
}

extern "C" void kernel_launch(void* const* d_in, const int* in_sizes, int n_in,
                              void* d_out, int out_size, void* d_ws, size_t ws_size,
                              hipStream_t stream) {
    const int B = in_sizes[0] / 256;  // 1024

    const size_t need = (size_t)B * 512 * 4 + (size_t)B * 10 * 512 * 4;  // 22.5 MB @ B=1024
    if (ws_size >= need) {
        float* h0_ws = (float*)d_ws;                  // (B, 512) fp32
        float* h1_ws = h0_ws + (size_t)B * 512;       // (B*10, 512) fp32
        gat_layer0<<<B * 11, 256, 0, stream>>>(d_in[0], d_in[1], d_in[2], d_in[3],
                                               d_in[4], d_in[5], h0_ws, h1_ws, B);
        gat_layer1<<<B, 256, 0, stream>>>(h0_ws, h1_ws, d_in[6], d_in[7], d_in[8],
                                          d_in[9], d_out);
    } else {
        gat_fused<<<B, 256, 0, stream>>>(d_in[0], d_in[1], d_in[2], d_in[3], d_in[4],
                                         d_in[5], d_in[6], d_in[7], d_in[8], d_in[9],
                                         d_out);
    }
}